// Round 2
// baseline (828.674 us; speedup 1.0000x reference)
//
#include <hip/hip_runtime.h>

// ---------------------------------------------------------------------------
// ScaleDotProductAttention: q=Q@Wq^T+bq; k=K@Wk^T+bk; v=V@Wv^T+bv
// S = q@k^T/32 (mask==1 -> -inf), P=softmax(S), out = P@v
// B=8, L1=L2=2048, D=E=1024. All matmuls via bf16 MFMA 16x16x32, fp32 accum.
// Round 1: per-batch streaming of S/P to keep d_ws footprint at 130 MB
// (round 0 used 322 MB -> suspected ws overflow -> GPU memory fault).
// ---------------------------------------------------------------------------

using u16 = unsigned short;
using frag_ab = __attribute__((ext_vector_type(8))) short;   // 8 bf16 (4 VGPRs)
using frag_cd = __attribute__((ext_vector_type(4))) float;   // 4 fp32

#define BM 128
#define BN 128
#define BK 64

__device__ __forceinline__ u16 f2bf(float f) {
  union { float f; unsigned u; } c; c.f = f;
  unsigned u = c.u;
  return (u16)((u + 0x7FFFu + ((u >> 16) & 1u)) >> 16);   // RNE
}

__device__ __forceinline__ void async_ld16(const void* g, void* l) {
  __builtin_amdgcn_global_load_lds(
      (const __attribute__((address_space(1))) unsigned*)g,
      (__attribute__((address_space(3))) unsigned*)l, 16, 0, 0);
}

// fp32 -> bf16 bits, 4 elems/thread, exact-division grids
__global__ void cvt_f32_bf16(const float* __restrict__ in, u16* __restrict__ out, long n) {
  long i = ((long)blockIdx.x * 256 + threadIdx.x) * 4;
  if (i >= n) return;
  float4 v = *reinterpret_cast<const float4*>(in + i);
  ushort4 o = make_ushort4(f2bf(v.x), f2bf(v.y), f2bf(v.z), f2bf(v.w));
  *reinterpret_cast<ushort4*>(out + i) = o;
}

// C = scale * (A @ Bt^T) + bias.  A:[M][K] bf16, Bt:[N][K] bf16 (both row-major).
// OUT_MODE: 0 = fp32 C[M][N], 1 = bf16 C[M][N], 2 = bf16 transposed-per-batch
//           (vT[b][n][l2] with b=row>>11, l2=row&2047; used for the v projection)
template<int OUT_MODE>
__global__ void __launch_bounds__(256, 2)
gemm_bt(const u16* __restrict__ A, const u16* __restrict__ Bt,
        void* __restrict__ Cout, const float* __restrict__ bias,
        int M, int N, int K, long sA, long sB, long sC, float scale)
{
  __shared__ u16 As[BM * BK];
  __shared__ u16 Bs[BN * BK];

  const int z = blockIdx.z;
  const u16* Ab = A + (long)z * sA;
  const u16* Bb = Bt + (long)z * sB;

  const int m0 = blockIdx.y * BM;
  const int n0 = blockIdx.x * BN;
  const int tid = threadIdx.x;
  const int wave = tid >> 6;
  const int lane = tid & 63;
  const int wr = wave >> 1;   // wave row 0..1 (64 rows each)
  const int wc = wave & 1;    // wave col 0..1 (64 cols each)

  frag_cd acc[4][4];
  #pragma unroll
  for (int i = 0; i < 4; i++)
    #pragma unroll
    for (int j = 0; j < 4; j++)
      acc[i][j] = (frag_cd){0.f, 0.f, 0.f, 0.f};

  const int srow = lane >> 3;          // 0..7 within 8-row chunk
  const int scol = (lane & 7) * 8;     // 0,8,..,56

  for (int k0 = 0; k0 < K; k0 += BK) {
    // stage A and Bt tiles: 16 chunks of 8 rows x 64 cols; chunk = i*4+wave
    #pragma unroll
    for (int i = 0; i < 4; i++) {
      const int c = i * 4 + wave;
      const int r = c * 8 + srow;
      async_ld16(Ab + (long)(m0 + r) * K + k0 + scol, &As[c * 512]);
      async_ld16(Bb + (long)(n0 + r) * K + k0 + scol, &Bs[c * 512]);
    }
    __syncthreads();

    #pragma unroll
    for (int s = 0; s < 2; s++) {
      const int kc = s * 32 + (lane >> 4) * 8;
      frag_ab av[4], bvv[4];
      #pragma unroll
      for (int i = 0; i < 4; i++) {
        const int row = wr * 64 + i * 16 + (lane & 15);
        av[i] = *reinterpret_cast<const frag_ab*>(&As[row * BK + kc]);
      }
      #pragma unroll
      for (int j = 0; j < 4; j++) {
        const int row = wc * 64 + j * 16 + (lane & 15);
        bvv[j] = *reinterpret_cast<const frag_ab*>(&Bs[row * BK + kc]);
      }
      #pragma unroll
      for (int i = 0; i < 4; i++)
        #pragma unroll
        for (int j = 0; j < 4; j++)
          acc[i][j] = __builtin_amdgcn_mfma_f32_16x16x32_bf16(av[i], bvv[j], acc[i][j], 0, 0, 0);
    }
    __syncthreads();
  }

  // epilogue: C/D layout col=lane&15, row=(lane>>4)*4 + r
  const int cl = lane & 15;
  const int rb = (lane >> 4) * 4;
  #pragma unroll
  for (int j = 0; j < 4; j++) {
    const int gcol = n0 + wc * 64 + j * 16 + cl;
    const float badd = bias ? bias[gcol] : 0.f;
    #pragma unroll
    for (int i = 0; i < 4; i++) {
      #pragma unroll
      for (int r = 0; r < 4; r++) {
        const int grow = m0 + wr * 64 + i * 16 + rb + r;
        const float val = acc[i][j][r] * scale + badd;
        if (OUT_MODE == 0) {
          ((float*)Cout)[(long)z * sC + (long)grow * N + gcol] = val;
        } else if (OUT_MODE == 1) {
          ((u16*)Cout)[(long)z * sC + (long)grow * N + gcol] = f2bf(val);
        } else {
          const int bb = grow >> 11, l2 = grow & 2047;
          ((u16*)Cout)[((long)bb * N + gcol) * 2048 + l2] = f2bf(val);
        }
      }
    }
  }
}

// one block (256 thr) per row of S[2048][2048] for ONE batch; mask==1 -> excluded
__global__ void softmax_rows(const float* __restrict__ S, const int* __restrict__ mask,
                             u16* __restrict__ P)
{
  const long row = blockIdx.x;
  const float* s = S + row * 2048;
  u16* p = P + row * 2048;

  const int t = threadIdx.x;
  const int base = t * 8;

  float4 v0 = *reinterpret_cast<const float4*>(s + base);
  float4 v1 = *reinterpret_cast<const float4*>(s + base + 4);
  int4 mA = *reinterpret_cast<const int4*>(mask + base);
  int4 mB = *reinterpret_cast<const int4*>(mask + base + 4);

  float vals[8] = {v0.x, v0.y, v0.z, v0.w, v1.x, v1.y, v1.z, v1.w};
  const int mk[8] = {mA.x, mA.y, mA.z, mA.w, mB.x, mB.y, mB.z, mB.w};

  float mx = -3.0e38f;
  #pragma unroll
  for (int i = 0; i < 8; i++) if (!mk[i]) mx = fmaxf(mx, vals[i]);
  #pragma unroll
  for (int off = 32; off > 0; off >>= 1) mx = fmaxf(mx, __shfl_xor(mx, off));

  __shared__ float redm[4], reds[4];
  const int wave = t >> 6, lane = t & 63;
  if (lane == 0) redm[wave] = mx;
  __syncthreads();
  mx = fmaxf(fmaxf(redm[0], redm[1]), fmaxf(redm[2], redm[3]));

  float e[8]; float sum = 0.f;
  #pragma unroll
  for (int i = 0; i < 8; i++) { e[i] = mk[i] ? 0.f : __expf(vals[i] - mx); sum += e[i]; }
  #pragma unroll
  for (int off = 32; off > 0; off >>= 1) sum += __shfl_xor(sum, off);
  if (lane == 0) reds[wave] = sum;
  __syncthreads();
  sum = reds[0] + reds[1] + reds[2] + reds[3];
  const float inv = 1.f / sum;

  ushort4 o0 = make_ushort4(f2bf(e[0]*inv), f2bf(e[1]*inv), f2bf(e[2]*inv), f2bf(e[3]*inv));
  ushort4 o1 = make_ushort4(f2bf(e[4]*inv), f2bf(e[5]*inv), f2bf(e[6]*inv), f2bf(e[7]*inv));
  *reinterpret_cast<ushort4*>(p + base) = o0;
  *reinterpret_cast<ushort4*>(p + base + 4) = o1;
}

extern "C" void kernel_launch(void* const* d_in, const int* in_sizes, int n_in,
                              void* d_out, int out_size, void* d_ws, size_t ws_size,
                              hipStream_t stream) {
  (void)in_sizes; (void)n_in; (void)out_size; (void)ws_size;

  const float* Qin  = (const float*)d_in[0];
  const float* Kin  = (const float*)d_in[1];
  const float* Vin  = (const float*)d_in[2];
  const int*   Kmask = (const int*)d_in[3];
  const float* Wq = (const float*)d_in[4];
  const float* bq = (const float*)d_in[5];
  const float* Wk = (const float*)d_in[6];
  const float* bk = (const float*)d_in[7];
  const float* Wv = (const float*)d_in[8];
  const float* bv = (const float*)d_in[9];

  // 130 MB workspace layout (buffers reused across phases):
  //   [0,32)    qb   bf16 [8*2048][1024]
  //   [32,64)   kb   bf16 [8*2048][1024]
  //   [64,96)   vT   bf16 [8][1024][2048]
  //   [96,128)  Xb   bf16 staging (projections)  ->  S fp32 [2048][2048] (16MB)
  //                                               +  P bf16 [2048][2048] (8MB)
  //   [128,130) Wb   bf16 weight staging
  char* ws = (char*)d_ws;
  const size_t MB = 1024UL * 1024UL;
  u16*  qb = (u16*)(ws);
  u16*  kb = (u16*)(ws + 32 * MB);
  u16*  vT = (u16*)(ws + 64 * MB);
  u16*  Xb = (u16*)(ws + 96 * MB);
  float* S = (float*)(ws + 96 * MB);
  u16*  P  = (u16*)(ws + 112 * MB);
  u16*  Wb = (u16*)(ws + 128 * MB);

  const long NQKV = 8L * 2048 * 1024;
  const long NW = 1024L * 1024;
  const dim3 blk(256);
  const float rs = 0.03125f;  // 1/sqrt(1024)

  // ---- projections: x @ W^T + b -> bf16 ----
  cvt_f32_bf16<<<dim3(NQKV / 1024), blk, 0, stream>>>(Qin, Xb, NQKV);
  cvt_f32_bf16<<<dim3(NW / 1024), blk, 0, stream>>>(Wq, Wb, NW);
  gemm_bt<1><<<dim3(8, 128, 1), blk, 0, stream>>>(Xb, Wb, qb, bq,
      16384, 1024, 1024, 0, 0, 0, 1.f);

  cvt_f32_bf16<<<dim3(NQKV / 1024), blk, 0, stream>>>(Kin, Xb, NQKV);
  cvt_f32_bf16<<<dim3(NW / 1024), blk, 0, stream>>>(Wk, Wb, NW);
  gemm_bt<1><<<dim3(8, 128, 1), blk, 0, stream>>>(Xb, Wb, kb, bk,
      16384, 1024, 1024, 0, 0, 0, 1.f);

  cvt_f32_bf16<<<dim3(NQKV / 1024), blk, 0, stream>>>(Vin, Xb, NQKV);
  cvt_f32_bf16<<<dim3(NW / 1024), blk, 0, stream>>>(Wv, Wb, NW);
  gemm_bt<2><<<dim3(8, 128, 1), blk, 0, stream>>>(Xb, Wb, vT, bv,
      16384, 1024, 1024, 0, 0, 0, 1.f);

  // ---- attention, one batch at a time (S/P streamed through 24 MB scratch) ----
  for (int b = 0; b < 8; b++) {
    const u16* qbB = qb + (long)b * 2048 * 1024;
    const u16* kbB = kb + (long)b * 2048 * 1024;
    const u16* vTB = vT + (long)b * 1024 * 2048;
    const int* mB  = Kmask + (long)b * 2048;
    float* outB = (float*)d_out + (long)b * 2048 * 1024;

    // S = q @ k^T / 32  (fp32)
    gemm_bt<0><<<dim3(16, 16, 1), blk, 0, stream>>>(qbB, kbB, S, nullptr,
        2048, 2048, 1024, 0, 0, 0, rs);

    // masked softmax rows -> P bf16
    softmax_rows<<<dim3(2048), blk, 0, stream>>>(S, mB, P);

    // out = P @ v = P @ vT^T  (fp32)
    gemm_bt<0><<<dim3(8, 16, 1), blk, 0, stream>>>(P, vTB, outB, nullptr,
        2048, 1024, 2048, 0, 0, 0, 1.f);
  }
}

// Round 3
// 502.322 us; speedup vs baseline: 1.6497x; 1.6497x over previous
//
#include <hip/hip_runtime.h>

// ---------------------------------------------------------------------------
// ScaleDotProductAttention: q=Q@Wq^T+bq; k=K@Wk^T+bk; v=V@Wv^T+bv
// S = q@k^T/32 (mask==1 -> -inf), P=softmax(S), out = P@v
// B=8, L1=L2=2048, D=E=1024. All matmuls via bf16 MFMA 16x16x32, fp32 accum.
// Round 2: batched-PV schedule (needs 194 MB ws, runtime-guarded with
// fallback to the per-batch streaming schedule) + bijective XCD swizzle.
// ---------------------------------------------------------------------------

using u16 = unsigned short;
using frag_ab = __attribute__((ext_vector_type(8))) short;   // 8 bf16 (4 VGPRs)
using frag_cd = __attribute__((ext_vector_type(4))) float;   // 4 fp32

#define BM 128
#define BN 128
#define BK 64

__device__ __forceinline__ u16 f2bf(float f) {
  union { float f; unsigned u; } c; c.f = f;
  unsigned u = c.u;
  return (u16)((u + 0x7FFFu + ((u >> 16) & 1u)) >> 16);   // RNE
}

__device__ __forceinline__ void async_ld16(const void* g, void* l) {
  __builtin_amdgcn_global_load_lds(
      (const __attribute__((address_space(1))) unsigned*)g,
      (__attribute__((address_space(3))) unsigned*)l, 16, 0, 0);
}

// fp32 -> bf16 bits, 4 elems/thread, exact-division grids
__global__ void cvt_f32_bf16(const float* __restrict__ in, u16* __restrict__ out, long n) {
  long i = ((long)blockIdx.x * 256 + threadIdx.x) * 4;
  if (i >= n) return;
  float4 v = *reinterpret_cast<const float4*>(in + i);
  ushort4 o = make_ushort4(f2bf(v.x), f2bf(v.y), f2bf(v.z), f2bf(v.w));
  *reinterpret_cast<ushort4*>(out + i) = o;
}

// C = scale * (A @ Bt^T) + bias.  A:[M][K] bf16, Bt:[N][K] bf16 (both row-major).
// OUT_MODE: 0 = fp32 C[M][N], 1 = bf16 C[M][N], 2 = bf16 transposed-per-batch
//           (vT[b][n][l2] with b=row>>11, l2=row&2047; used for the v projection)
// blockIdx.z = batch with element strides sA/sB/sC.
// Bijective XCD swizzle (m204) on the per-z linear block id for L2 locality.
template<int OUT_MODE>
__global__ void __launch_bounds__(256, 2)
gemm_bt(const u16* __restrict__ A, const u16* __restrict__ Bt,
        void* __restrict__ Cout, const float* __restrict__ bias,
        int M, int N, int K, long sA, long sB, long sC, float scale)
{
  __shared__ u16 As[BM * BK];
  __shared__ u16 Bs[BN * BK];

  const int z = blockIdx.z;
  const u16* Ab = A + (long)z * sA;
  const u16* Bb = Bt + (long)z * sB;

  // ---- bijective XCD swizzle within the z-slice ----
  const int gx = gridDim.x;
  const int nwg = gx * gridDim.y;
  const int lin = blockIdx.y * gx + blockIdx.x;
  const int q8 = nwg >> 3, r8 = nwg & 7;
  const int xcd = lin & 7, idx = lin >> 3;
  const int swz = (xcd < r8 ? xcd * (q8 + 1) : r8 * (q8 + 1) + (xcd - r8) * q8) + idx;
  const int m0 = (swz / gx) * BM;
  const int n0 = (swz % gx) * BN;

  const int tid = threadIdx.x;
  const int wave = tid >> 6;
  const int lane = tid & 63;
  const int wr = wave >> 1;   // wave row 0..1 (64 rows each)
  const int wc = wave & 1;    // wave col 0..1 (64 cols each)

  frag_cd acc[4][4];
  #pragma unroll
  for (int i = 0; i < 4; i++)
    #pragma unroll
    for (int j = 0; j < 4; j++)
      acc[i][j] = (frag_cd){0.f, 0.f, 0.f, 0.f};

  const int srow = lane >> 3;          // 0..7 within 8-row chunk
  const int scol = (lane & 7) * 8;     // 0,8,..,56

  for (int k0 = 0; k0 < K; k0 += BK) {
    // stage A and Bt tiles: 16 chunks of 8 rows x 64 cols; chunk = i*4+wave
    #pragma unroll
    for (int i = 0; i < 4; i++) {
      const int c = i * 4 + wave;
      const int r = c * 8 + srow;
      async_ld16(Ab + (long)(m0 + r) * K + k0 + scol, &As[c * 512]);
      async_ld16(Bb + (long)(n0 + r) * K + k0 + scol, &Bs[c * 512]);
    }
    __syncthreads();

    #pragma unroll
    for (int s = 0; s < 2; s++) {
      const int kc = s * 32 + (lane >> 4) * 8;
      frag_ab av[4], bvv[4];
      #pragma unroll
      for (int i = 0; i < 4; i++) {
        const int row = wr * 64 + i * 16 + (lane & 15);
        av[i] = *reinterpret_cast<const frag_ab*>(&As[row * BK + kc]);
      }
      #pragma unroll
      for (int j = 0; j < 4; j++) {
        const int row = wc * 64 + j * 16 + (lane & 15);
        bvv[j] = *reinterpret_cast<const frag_ab*>(&Bs[row * BK + kc]);
      }
      #pragma unroll
      for (int i = 0; i < 4; i++)
        #pragma unroll
        for (int j = 0; j < 4; j++)
          acc[i][j] = __builtin_amdgcn_mfma_f32_16x16x32_bf16(av[i], bvv[j], acc[i][j], 0, 0, 0);
    }
    __syncthreads();
  }

  // epilogue: C/D layout col=lane&15, row=(lane>>4)*4 + r
  const int cl = lane & 15;
  const int rb = (lane >> 4) * 4;
  #pragma unroll
  for (int j = 0; j < 4; j++) {
    const int gcol = n0 + wc * 64 + j * 16 + cl;
    const float badd = bias ? bias[gcol] : 0.f;
    #pragma unroll
    for (int i = 0; i < 4; i++) {
      #pragma unroll
      for (int r = 0; r < 4; r++) {
        const int grow = m0 + wr * 64 + i * 16 + rb + r;
        const float val = acc[i][j][r] * scale + badd;
        if (OUT_MODE == 0) {
          ((float*)Cout)[(long)z * sC + (long)grow * N + gcol] = val;
        } else if (OUT_MODE == 1) {
          ((u16*)Cout)[(long)z * sC + (long)grow * N + gcol] = f2bf(val);
        } else {
          const int bb = grow >> 11, l2 = grow & 2047;
          ((u16*)Cout)[((long)bb * N + gcol) * 2048 + l2] = f2bf(val);
        }
      }
    }
  }
}

// one block (256 thr) per row of S[2048][2048] for ONE batch; mask==1 -> excluded
__global__ void softmax_rows(const float* __restrict__ S, const int* __restrict__ mask,
                             u16* __restrict__ P)
{
  const long row = blockIdx.x;
  const float* s = S + row * 2048;
  u16* p = P + row * 2048;

  const int t = threadIdx.x;
  const int base = t * 8;

  float4 v0 = *reinterpret_cast<const float4*>(s + base);
  float4 v1 = *reinterpret_cast<const float4*>(s + base + 4);
  int4 mA = *reinterpret_cast<const int4*>(mask + base);
  int4 mB = *reinterpret_cast<const int4*>(mask + base + 4);

  float vals[8] = {v0.x, v0.y, v0.z, v0.w, v1.x, v1.y, v1.z, v1.w};
  const int mk[8] = {mA.x, mA.y, mA.z, mA.w, mB.x, mB.y, mB.z, mB.w};

  float mx = -3.0e38f;
  #pragma unroll
  for (int i = 0; i < 8; i++) if (!mk[i]) mx = fmaxf(mx, vals[i]);
  #pragma unroll
  for (int off = 32; off > 0; off >>= 1) mx = fmaxf(mx, __shfl_xor(mx, off));

  __shared__ float redm[4], reds[4];
  const int wave = t >> 6, lane = t & 63;
  if (lane == 0) redm[wave] = mx;
  __syncthreads();
  mx = fmaxf(fmaxf(redm[0], redm[1]), fmaxf(redm[2], redm[3]));

  float e[8]; float sum = 0.f;
  #pragma unroll
  for (int i = 0; i < 8; i++) { e[i] = mk[i] ? 0.f : __expf(vals[i] - mx); sum += e[i]; }
  #pragma unroll
  for (int off = 32; off > 0; off >>= 1) sum += __shfl_xor(sum, off);
  if (lane == 0) reds[wave] = sum;
  __syncthreads();
  sum = reds[0] + reds[1] + reds[2] + reds[3];
  const float inv = 1.f / sum;

  ushort4 o0 = make_ushort4(f2bf(e[0]*inv), f2bf(e[1]*inv), f2bf(e[2]*inv), f2bf(e[3]*inv));
  ushort4 o1 = make_ushort4(f2bf(e[4]*inv), f2bf(e[5]*inv), f2bf(e[6]*inv), f2bf(e[7]*inv));
  *reinterpret_cast<ushort4*>(p + base) = o0;
  *reinterpret_cast<ushort4*>(p + base + 4) = o1;
}

extern "C" void kernel_launch(void* const* d_in, const int* in_sizes, int n_in,
                              void* d_out, int out_size, void* d_ws, size_t ws_size,
                              hipStream_t stream) {
  (void)in_sizes; (void)n_in; (void)out_size;

  const float* Qin  = (const float*)d_in[0];
  const float* Kin  = (const float*)d_in[1];
  const float* Vin  = (const float*)d_in[2];
  const int*   Kmask = (const int*)d_in[3];
  const float* Wq = (const float*)d_in[4];
  const float* bq = (const float*)d_in[5];
  const float* Wk = (const float*)d_in[6];
  const float* bk = (const float*)d_in[7];
  const float* Wv = (const float*)d_in[8];
  const float* bv = (const float*)d_in[9];

  char* ws = (char*)d_ws;
  const size_t MB = 1024UL * 1024UL;
  const long NQKV = 8L * 2048 * 1024;
  const long NW = 1024L * 1024;
  const dim3 blk(256);
  const float rs = 0.03125f;  // 1/sqrt(1024)

  if (ws_size >= 194 * MB) {
    // ---- fast schedule: 194 MB layout ----
    //   [0,32)    qb  bf16 [8*2048][1024]
    //   [32,64)   kb  bf16 [8*2048][1024]
    //   [64,96)   vT  bf16 [8][1024][2048]
    //   [96,160)  P   bf16 [8][2048][2048]   (head reused as Xb during proj)
    //   [160,192) S   fp32 [2][2048][2048]   (batch pair)
    //   [192,194) Wb  bf16 weight staging
    u16*  qb = (u16*)(ws);
    u16*  kb = (u16*)(ws + 32 * MB);
    u16*  vT = (u16*)(ws + 64 * MB);
    u16*  P  = (u16*)(ws + 96 * MB);
    u16*  Xb = (u16*)(ws + 96 * MB);
    float* S = (float*)(ws + 160 * MB);
    u16*  Wb = (u16*)(ws + 192 * MB);

    // projections
    cvt_f32_bf16<<<dim3(NQKV / 1024), blk, 0, stream>>>(Qin, Xb, NQKV);
    cvt_f32_bf16<<<dim3(NW / 1024), blk, 0, stream>>>(Wq, Wb, NW);
    gemm_bt<1><<<dim3(8, 128, 1), blk, 0, stream>>>(Xb, Wb, qb, bq,
        16384, 1024, 1024, 0, 0, 0, 1.f);

    cvt_f32_bf16<<<dim3(NQKV / 1024), blk, 0, stream>>>(Kin, Xb, NQKV);
    cvt_f32_bf16<<<dim3(NW / 1024), blk, 0, stream>>>(Wk, Wb, NW);
    gemm_bt<1><<<dim3(8, 128, 1), blk, 0, stream>>>(Xb, Wb, kb, bk,
        16384, 1024, 1024, 0, 0, 0, 1.f);

    cvt_f32_bf16<<<dim3(NQKV / 1024), blk, 0, stream>>>(Vin, Xb, NQKV);
    cvt_f32_bf16<<<dim3(NW / 1024), blk, 0, stream>>>(Wv, Wb, NW);
    gemm_bt<2><<<dim3(8, 128, 1), blk, 0, stream>>>(Xb, Wb, vT, bv,
        16384, 1024, 1024, 0, 0, 0, 1.f);

    // scores + softmax, two batches per S buffer
    for (int p = 0; p < 4; p++) {
      const u16* qbP = qb + (long)(2 * p) * 2048 * 1024;
      const u16* kbP = kb + (long)(2 * p) * 2048 * 1024;
      gemm_bt<0><<<dim3(16, 16, 2), blk, 0, stream>>>(qbP, kbP, S, nullptr,
          2048, 2048, 1024, 2048L * 1024, 2048L * 1024, 2048L * 2048, rs);
      for (int zz = 0; zz < 2; zz++) {
        const int b = 2 * p + zz;
        softmax_rows<<<dim3(2048), blk, 0, stream>>>(
            S + (long)zz * 2048 * 2048, Kmask + (long)b * 2048,
            P + (long)b * 2048 * 2048);
      }
    }

    // out = P @ vT^T, all 8 batches in one dispatch (1024 blocks)
    gemm_bt<0><<<dim3(8, 16, 8), blk, 0, stream>>>(P, vT, d_out, nullptr,
        2048, 1024, 2048, 2048L * 2048, 1024L * 2048, 2048L * 1024, 1.f);
  } else {
    // ---- fallback: round-2 streaming schedule, 130 MB ----
    u16*  qb = (u16*)(ws);
    u16*  kb = (u16*)(ws + 32 * MB);
    u16*  vT = (u16*)(ws + 64 * MB);
    u16*  Xb = (u16*)(ws + 96 * MB);
    float* S = (float*)(ws + 96 * MB);
    u16*  P  = (u16*)(ws + 112 * MB);
    u16*  Wb = (u16*)(ws + 128 * MB);

    cvt_f32_bf16<<<dim3(NQKV / 1024), blk, 0, stream>>>(Qin, Xb, NQKV);
    cvt_f32_bf16<<<dim3(NW / 1024), blk, 0, stream>>>(Wq, Wb, NW);
    gemm_bt<1><<<dim3(8, 128, 1), blk, 0, stream>>>(Xb, Wb, qb, bq,
        16384, 1024, 1024, 0, 0, 0, 1.f);

    cvt_f32_bf16<<<dim3(NQKV / 1024), blk, 0, stream>>>(Kin, Xb, NQKV);
    cvt_f32_bf16<<<dim3(NW / 1024), blk, 0, stream>>>(Wk, Wb, NW);
    gemm_bt<1><<<dim3(8, 128, 1), blk, 0, stream>>>(Xb, Wb, kb, bk,
        16384, 1024, 1024, 0, 0, 0, 1.f);

    cvt_f32_bf16<<<dim3(NQKV / 1024), blk, 0, stream>>>(Vin, Xb, NQKV);
    cvt_f32_bf16<<<dim3(NW / 1024), blk, 0, stream>>>(Wv, Wb, NW);
    gemm_bt<2><<<dim3(8, 128, 1), blk, 0, stream>>>(Xb, Wb, vT, bv,
        16384, 1024, 1024, 0, 0, 0, 1.f);

    for (int b = 0; b < 8; b++) {
      const u16* qbB = qb + (long)b * 2048 * 1024;
      const u16* kbB = kb + (long)b * 2048 * 1024;
      const u16* vTB = vT + (long)b * 1024 * 2048;
      const int* mB  = Kmask + (long)b * 2048;
      float* outB = (float*)d_out + (long)b * 2048 * 1024;

      gemm_bt<0><<<dim3(16, 16, 1), blk, 0, stream>>>(qbB, kbB, S, nullptr,
          2048, 2048, 1024, 0, 0, 0, rs);
      softmax_rows<<<dim3(2048), blk, 0, stream>>>(S, mB, P);
      gemm_bt<0><<<dim3(8, 16, 1), blk, 0, stream>>>(P, vTB, outB, nullptr,
          2048, 1024, 2048, 0, 0, 0, 1.f);
    }
  }
}

// Round 4
// 472.849 us; speedup vs baseline: 1.7525x; 1.0623x over previous
//
#include <hip/hip_runtime.h>

// ---------------------------------------------------------------------------
// ScaleDotProductAttention: q=Q@Wq^T+bq; k=K@Wk^T+bk; v=V@Wv^T+bv
// S = q@k^T/32 (mask==1 -> -inf), P=softmax(S), out = P@v
// B=8, L1=L2=2048, D=E=1024. bf16 MFMA 16x16x32, fp32 accum.
// Round 4: 256x256 8-phase GEMM (T2 swizzle + T3/T4 counted vmcnt + T5
// setprio), replacing the 128^2 2-barrier structure. Schedule unchanged.
// ---------------------------------------------------------------------------

using u16 = unsigned short;
using frag_ab = __attribute__((ext_vector_type(8))) short;   // 8 bf16 (4 VGPRs)
using frag_cd = __attribute__((ext_vector_type(4))) float;   // 4 fp32

#define BAR() asm volatile("s_barrier" ::: "memory")
#define WAITV(n) asm volatile("s_waitcnt vmcnt(" #n ")" ::: "memory")

__device__ __forceinline__ u16 f2bf(float f) {
  union { float f; unsigned u; } c; c.f = f;
  unsigned u = c.u;
  return (u16)((u + 0x7FFFu + ((u >> 16) & 1u)) >> 16);   // RNE
}

__device__ __forceinline__ void async_ld16(const void* g, void* l) {
  __builtin_amdgcn_global_load_lds(
      (const __attribute__((address_space(1))) unsigned*)g,
      (__attribute__((address_space(3))) unsigned*)l, 16, 0, 0);
}

// fp32 -> bf16 bits, 4 elems/thread
__global__ void cvt_f32_bf16(const float* __restrict__ in, u16* __restrict__ out, long n) {
  long i = ((long)blockIdx.x * 256 + threadIdx.x) * 4;
  if (i >= n) return;
  float4 v = *reinterpret_cast<const float4*>(in + i);
  ushort4 o = make_ushort4(f2bf(v.x), f2bf(v.y), f2bf(v.z), f2bf(v.w));
  *reinterpret_cast<ushort4*>(out + i) = o;
}

// Stage one 128x64 bf16 half-tile: linear LDS dest (global_load_lds
// requirement), st_16x32 swizzle pre-applied to the GLOBAL source column
// (involution; read side applies the same XOR). 2 issues x 512 thr x 16B.
__device__ __forceinline__ void stage_half(const u16* __restrict__ g_rowbase,
                                           long Kstr, u16* l_half,
                                           int wave, int lane) {
  const int t = wave * 64 + lane;
  #pragma unroll
  for (int i = 0; i < 2; i++) {
    const int row = i * 64 + (t >> 3);
    const int cb  = (t & 7) * 16;                      // byte col 0..112
    const int cbs = cb ^ (((row >> 2) & 1) << 5);      // st_16x32 swizzle
    async_ld16(g_rowbase + (long)row * Kstr + (cbs >> 1),
               l_half + i * 4096 + wave * 512);        // wave-uniform dest
  }
}

// swizzled fragment read: 8 bf16 at (row r, k..k+7) of a [128][64] half
__device__ __forceinline__ frag_ab ld_frag(const u16* half_base, int r, int k) {
  const int idx = r * 64 + (k ^ (((r >> 2) & 1) << 4));
  return *reinterpret_cast<const frag_ab*>(half_base + idx);
}

// C = scale * (A @ Bt^T) + bias.  A:[M][K] bf16, Bt:[N][K] bf16 row-major.
// OUT_MODE: 0 fp32 C[M][N]; 1 bf16 C[M][N]; 2 bf16 vT[b][n][l2] (b=row>>11).
// 256x256 tile, BK=64, 8 waves (2M x 4N), 128KB LDS double-buffer, 4 phases
// per K-tile (8 per 2 K-tiles), counted vmcnt(4) once per K-tile.
template<int OUT_MODE>
__global__ void __launch_bounds__(512, 2)
gemm256(const u16* __restrict__ A, const u16* __restrict__ Bt,
        void* __restrict__ Cout, const float* __restrict__ bias,
        int M, int N, int K, long sA, long sB, long sC, float scale)
{
  __shared__ u16 lds[2][2][2][8192];   // [dbuf][A=0/B=1][half][128*64]

  const int z = blockIdx.z;
  const u16* Ab = A + (long)z * sA;
  const u16* Bb = Bt + (long)z * sB;

  // bijective XCD swizzle within the z-slice (m204)
  const int gx = gridDim.x;
  const int nwg = gx * gridDim.y;
  const int lin = blockIdx.y * gx + blockIdx.x;
  const int q8 = nwg >> 3, r8 = nwg & 7;
  const int xcd = lin & 7, idx8 = lin >> 3;
  const int swz = (xcd < r8 ? xcd * (q8 + 1) : r8 * (q8 + 1) + (xcd - r8) * q8) + idx8;
  const int m0 = (swz / gx) * 256;
  const int n0 = (swz % gx) * 256;

  const int tid = threadIdx.x;
  const int wave = tid >> 6, lane = tid & 63;
  const int wm = wave >> 2;        // 0..1 : rows wm*128..+127
  const int wn = wave & 3;         // 0..3 : cols wn*64..+63
  const int ln15 = lane & 15, kof = (lane >> 4) * 8;
  const int rB0 = (wn & 1) * 64;
  const int NT = K >> 6;

  frag_cd acc[8][4];
  #pragma unroll
  for (int i = 0; i < 8; i++)
    #pragma unroll
    for (int j = 0; j < 4; j++)
      acc[i][j] = (frag_cd){0.f, 0.f, 0.f, 0.f};

  // ---- prologue: tile0 all 4 halves + tile1 A-halves; wait 8 oldest ----
  stage_half(Ab + (long)(m0 +   0) * K, K, &lds[0][0][0][0], wave, lane);
  stage_half(Ab + (long)(m0 + 128) * K, K, &lds[0][0][1][0], wave, lane);
  stage_half(Bb + (long)(n0 +   0) * K, K, &lds[0][1][0][0], wave, lane);
  stage_half(Bb + (long)(n0 + 128) * K, K, &lds[0][1][1][0], wave, lane);
  {
    const int ts = (1 < NT) ? 1 : NT - 1;
    stage_half(Ab + (long)(m0 +   0) * K + ts * 64, K, &lds[1][0][0][0], wave, lane);
    stage_half(Ab + (long)(m0 + 128) * K + ts * 64, K, &lds[1][0][1][0], wave, lane);
  }
  WAITV(4);
  BAR();

  for (int t = 0; t < NT; ++t) {
    const int d = t & 1;
    const u16* Al = &lds[d][0][wm][0];
    const u16* Bl = &lds[d][1][wn >> 1][0];
    const int tb = (t + 1 < NT) ? t + 1 : NT - 1;   // B-staging source tile
    const int ta = (t + 2 < NT) ? t + 2 : NT - 1;   // A-staging source tile

    frag_ab bf[4][2], af[8][2];

    // ---- PHASE A: read B frags (8) + A quad0 (4); stage B-h0 of t+1 ----
    #pragma unroll
    for (int bn = 0; bn < 4; ++bn)
      #pragma unroll
      for (int kk = 0; kk < 2; ++kk)
        bf[bn][kk] = ld_frag(Bl, rB0 + bn * 16 + ln15, kk * 32 + kof);
    #pragma unroll
    for (int am = 0; am < 2; ++am)
      #pragma unroll
      for (int kk = 0; kk < 2; ++kk)
        af[am][kk] = ld_frag(Al, am * 16 + ln15, kk * 32 + kof);
    stage_half(Bb + (long)(n0 + 0) * K + tb * 64, K, &lds[d ^ 1][1][0][0], wave, lane);
    BAR();
    __builtin_amdgcn_s_setprio(1);
    #pragma unroll
    for (int am = 0; am < 2; ++am)
      #pragma unroll
      for (int bn = 0; bn < 4; ++bn)
        #pragma unroll
        for (int kk = 0; kk < 2; ++kk)
          acc[am][bn] = __builtin_amdgcn_mfma_f32_16x16x32_bf16(af[am][kk], bf[bn][kk], acc[am][bn], 0, 0, 0);
    __builtin_amdgcn_s_setprio(0);
    BAR();

    // ---- PHASE B: read A quads 1-3 (12); stage B-h1 of t+1 ----
    #pragma unroll
    for (int am = 2; am < 8; ++am)
      #pragma unroll
      for (int kk = 0; kk < 2; ++kk)
        af[am][kk] = ld_frag(Al, am * 16 + ln15, kk * 32 + kof);
    stage_half(Bb + (long)(n0 + 128) * K + tb * 64, K, &lds[d ^ 1][1][1][0], wave, lane);
    BAR();
    __builtin_amdgcn_s_setprio(1);
    #pragma unroll
    for (int am = 2; am < 4; ++am)
      #pragma unroll
      for (int bn = 0; bn < 4; ++bn)
        #pragma unroll
        for (int kk = 0; kk < 2; ++kk)
          acc[am][bn] = __builtin_amdgcn_mfma_f32_16x16x32_bf16(af[am][kk], bf[bn][kk], acc[am][bn], 0, 0, 0);
    __builtin_amdgcn_s_setprio(0);
    BAR();

    // ---- PHASE C: stage A-h0 of t+2 (into dbuf d, reads done) ----
    stage_half(Ab + (long)(m0 + 0) * K + ta * 64, K, &lds[d][0][0][0], wave, lane);
    BAR();
    __builtin_amdgcn_s_setprio(1);
    #pragma unroll
    for (int am = 4; am < 6; ++am)
      #pragma unroll
      for (int bn = 0; bn < 4; ++bn)
        #pragma unroll
        for (int kk = 0; kk < 2; ++kk)
          acc[am][bn] = __builtin_amdgcn_mfma_f32_16x16x32_bf16(af[am][kk], bf[bn][kk], acc[am][bn], 0, 0, 0);
    __builtin_amdgcn_s_setprio(0);
    BAR();

    // ---- PHASE D: stage A-h1 of t+2; counted vmcnt(4); tile barrier ----
    stage_half(Ab + (long)(m0 + 128) * K + ta * 64, K, &lds[d][0][1][0], wave, lane);
    BAR();
    __builtin_amdgcn_s_setprio(1);
    #pragma unroll
    for (int am = 6; am < 8; ++am)
      #pragma unroll
      for (int bn = 0; bn < 4; ++bn)
        #pragma unroll
        for (int kk = 0; kk < 2; ++kk)
          acc[am][bn] = __builtin_amdgcn_mfma_f32_16x16x32_bf16(af[am][kk], bf[bn][kk], acc[am][bn], 0, 0, 0);
    __builtin_amdgcn_s_setprio(0);
    WAITV(4);     // t+1's 4 B-half loads done; 4 newest (t+2 A-halves) in flight
    BAR();
  }

  WAITV(0);       // drain dummy tail prefetches before LDS goes away
  BAR();

  // ---- epilogue: C/D col=lane&15, row=(lane>>4)*4+r (verified mapping) ----
  const int cl = lane & 15;
  const int rb = (lane >> 4) * 4;
  #pragma unroll
  for (int bn = 0; bn < 4; ++bn) {
    const int gcol = n0 + wn * 64 + bn * 16 + cl;
    const float badd = bias ? bias[gcol] : 0.f;
    #pragma unroll
    for (int am = 0; am < 8; ++am) {
      #pragma unroll
      for (int r = 0; r < 4; ++r) {
        const int grow = m0 + wm * 128 + am * 16 + rb + r;
        const float val = acc[am][bn][r] * scale + badd;
        if (OUT_MODE == 0) {
          ((float*)Cout)[(long)z * sC + (long)grow * N + gcol] = val;
        } else if (OUT_MODE == 1) {
          ((u16*)Cout)[(long)z * sC + (long)grow * N + gcol] = f2bf(val);
        } else {
          const int bb = grow >> 11, l2 = grow & 2047;
          ((u16*)Cout)[((long)bb * N + gcol) * 2048 + l2] = f2bf(val);
        }
      }
    }
  }
}

// one block (256 thr) per row of S[2048][2048] for ONE batch; mask==1 excluded
__global__ void softmax_rows(const float* __restrict__ S, const int* __restrict__ mask,
                             u16* __restrict__ P)
{
  const long row = blockIdx.x;
  const float* s = S + row * 2048;
  u16* p = P + row * 2048;

  const int t = threadIdx.x;
  const int base = t * 8;

  float4 v0 = *reinterpret_cast<const float4*>(s + base);
  float4 v1 = *reinterpret_cast<const float4*>(s + base + 4);
  int4 mA = *reinterpret_cast<const int4*>(mask + base);
  int4 mB = *reinterpret_cast<const int4*>(mask + base + 4);

  float vals[8] = {v0.x, v0.y, v0.z, v0.w, v1.x, v1.y, v1.z, v1.w};
  const int mk[8] = {mA.x, mA.y, mA.z, mA.w, mB.x, mB.y, mB.z, mB.w};

  float mx = -3.0e38f;
  #pragma unroll
  for (int i = 0; i < 8; i++) if (!mk[i]) mx = fmaxf(mx, vals[i]);
  #pragma unroll
  for (int off = 32; off > 0; off >>= 1) mx = fmaxf(mx, __shfl_xor(mx, off));

  __shared__ float redm[4], reds[4];
  const int wave = t >> 6, lane = t & 63;
  if (lane == 0) redm[wave] = mx;
  __syncthreads();
  mx = fmaxf(fmaxf(redm[0], redm[1]), fmaxf(redm[2], redm[3]));

  float e[8]; float sum = 0.f;
  #pragma unroll
  for (int i = 0; i < 8; i++) { e[i] = mk[i] ? 0.f : __expf(vals[i] - mx); sum += e[i]; }
  #pragma unroll
  for (int off = 32; off > 0; off >>= 1) sum += __shfl_xor(sum, off);
  if (lane == 0) reds[wave] = sum;
  __syncthreads();
  sum = reds[0] + reds[1] + reds[2] + reds[3];
  const float inv = 1.f / sum;

  ushort4 o0 = make_ushort4(f2bf(e[0]*inv), f2bf(e[1]*inv), f2bf(e[2]*inv), f2bf(e[3]*inv));
  ushort4 o1 = make_ushort4(f2bf(e[4]*inv), f2bf(e[5]*inv), f2bf(e[6]*inv), f2bf(e[7]*inv));
  *reinterpret_cast<ushort4*>(p + base) = o0;
  *reinterpret_cast<ushort4*>(p + base + 4) = o1;
}

extern "C" void kernel_launch(void* const* d_in, const int* in_sizes, int n_in,
                              void* d_out, int out_size, void* d_ws, size_t ws_size,
                              hipStream_t stream) {
  (void)in_sizes; (void)n_in; (void)out_size; (void)ws_size;

  const float* Qin  = (const float*)d_in[0];
  const float* Kin  = (const float*)d_in[1];
  const float* Vin  = (const float*)d_in[2];
  const int*   Kmask = (const int*)d_in[3];
  const float* Wq = (const float*)d_in[4];
  const float* bq = (const float*)d_in[5];
  const float* Wk = (const float*)d_in[6];
  const float* bk = (const float*)d_in[7];
  const float* Wv = (const float*)d_in[8];
  const float* bv = (const float*)d_in[9];

  // 194 MB workspace layout (validated in round 3):
  //   [0,32)    qb  bf16 [8*2048][1024]
  //   [32,64)   kb  bf16 [8*2048][1024]
  //   [64,96)   vT  bf16 [8][1024][2048]
  //   [96,160)  P   bf16 [8][2048][2048]   (head reused as Xb during proj)
  //   [160,192) S   fp32 [2][2048][2048]
  //   [192,194) Wb  bf16 weight staging
  char* ws = (char*)d_ws;
  const size_t MB = 1024UL * 1024UL;
  u16*  qb = (u16*)(ws);
  u16*  kb = (u16*)(ws + 32 * MB);
  u16*  vT = (u16*)(ws + 64 * MB);
  u16*  P  = (u16*)(ws + 96 * MB);
  u16*  Xb = (u16*)(ws + 96 * MB);
  float* S = (float*)(ws + 160 * MB);
  u16*  Wb = (u16*)(ws + 192 * MB);

  const long NQKV = 8L * 2048 * 1024;
  const long NW = 1024L * 1024;
  const dim3 blk(256);
  const dim3 gblk(512);
  const float rs = 0.03125f;  // 1/sqrt(1024)

  // ---- projections: x @ W^T + b -> bf16 ----
  cvt_f32_bf16<<<dim3(NQKV / 1024), blk, 0, stream>>>(Qin, Xb, NQKV);
  cvt_f32_bf16<<<dim3(NW / 1024), blk, 0, stream>>>(Wq, Wb, NW);
  gemm256<1><<<dim3(4, 64, 1), gblk, 0, stream>>>(Xb, Wb, qb, bq,
      16384, 1024, 1024, 0, 0, 0, 1.f);

  cvt_f32_bf16<<<dim3(NQKV / 1024), blk, 0, stream>>>(Kin, Xb, NQKV);
  cvt_f32_bf16<<<dim3(NW / 1024), blk, 0, stream>>>(Wk, Wb, NW);
  gemm256<1><<<dim3(4, 64, 1), gblk, 0, stream>>>(Xb, Wb, kb, bk,
      16384, 1024, 1024, 0, 0, 0, 1.f);

  cvt_f32_bf16<<<dim3(NQKV / 1024), blk, 0, stream>>>(Vin, Xb, NQKV);
  cvt_f32_bf16<<<dim3(NW / 1024), blk, 0, stream>>>(Wv, Wb, NW);
  gemm256<2><<<dim3(4, 64, 1), gblk, 0, stream>>>(Xb, Wb, vT, bv,
      16384, 1024, 1024, 0, 0, 0, 1.f);

  // ---- scores + softmax, two batches per S buffer ----
  for (int p = 0; p < 4; p++) {
    const u16* qbP = qb + (long)(2 * p) * 2048 * 1024;
    const u16* kbP = kb + (long)(2 * p) * 2048 * 1024;
    gemm256<0><<<dim3(8, 8, 2), gblk, 0, stream>>>(qbP, kbP, S, nullptr,
        2048, 2048, 1024, 2048L * 1024, 2048L * 1024, 2048L * 2048, rs);
    for (int zz = 0; zz < 2; zz++) {
      const int b = 2 * p + zz;
      softmax_rows<<<dim3(2048), blk, 0, stream>>>(
          S + (long)zz * 2048 * 2048, Kmask + (long)b * 2048,
          P + (long)b * 2048 * 2048);
    }
  }

  // ---- out = P @ vT^T, all 8 batches in one dispatch ----
  gemm256<0><<<dim3(4, 8, 8), gblk, 0, stream>>>(P, vT, d_out, nullptr,
      2048, 1024, 2048, 2048L * 2048, 1024L * 2048, 2048L * 1024, 1.f);
}

// Round 5
// 388.742 us; speedup vs baseline: 2.1317x; 1.2164x over previous
//
#include <hip/hip_runtime.h>

// ---------------------------------------------------------------------------
// ScaleDotProductAttention: q=Q@Wq^T+bq; k=K@Wk^T+bk; v=V@Wv^T+bv
// S = q@k^T/32 (mask==1 -> -inf), P=softmax(S), out = P@v
// B=8, L1=L2=2048, D=E=1024. bf16 MFMA 16x16x32, fp32 accum.
// Round 5: 3-bit LDS XOR swizzle ((row&7)<<4, was 1-bit -> 8-way conflicts),
// z-folded bijective XCD swizzle, QK at z=4 (full-GPU grid, guarded 226MB
// layout), distinct kernel names per role for unambiguous profiling.
// ---------------------------------------------------------------------------

using u16 = unsigned short;
using frag_ab = __attribute__((ext_vector_type(8))) short;   // 8 bf16 (4 VGPRs)
using frag_cd = __attribute__((ext_vector_type(4))) float;   // 4 fp32

#define BAR() asm volatile("s_barrier" ::: "memory")
#define WAITV(n) asm volatile("s_waitcnt vmcnt(" #n ")" ::: "memory")
#define L(d, ab, h) (lds + (((d) * 4) + ((ab) * 2) + (h)) * 8192)

__device__ __forceinline__ u16 f2bf(float f) {
  union { float f; unsigned u; } c; c.f = f;
  unsigned u = c.u;
  return (u16)((u + 0x7FFFu + ((u >> 16) & 1u)) >> 16);   // RNE
}

__device__ __forceinline__ void async_ld16(const void* g, void* l) {
  __builtin_amdgcn_global_load_lds(
      (const __attribute__((address_space(1))) unsigned*)g,
      (__attribute__((address_space(3))) unsigned*)l, 16, 0, 0);
}

// fp32 -> bf16 bits, 4 elems/thread
__global__ void cvt_f32_bf16(const float* __restrict__ in, u16* __restrict__ out, long n) {
  long i = ((long)blockIdx.x * 256 + threadIdx.x) * 4;
  if (i >= n) return;
  float4 v = *reinterpret_cast<const float4*>(in + i);
  ushort4 o = make_ushort4(f2bf(v.x), f2bf(v.y), f2bf(v.z), f2bf(v.w));
  *reinterpret_cast<ushort4*>(out + i) = o;
}

// Stage one 128x64 bf16 half-tile. LDS dest linear (global_load_lds rule);
// 3-bit XOR swizzle (row&7)<<4 pre-applied to the GLOBAL source 16B-slot.
// Involution; ld_frag applies the same XOR. Spreads 16-row column reads
// over 8 banks-slots -> 2-way (free) instead of 8-way.
__device__ __forceinline__ void stage_half(const u16* __restrict__ g_rowbase,
                                           long Kstr, u16* l_half,
                                           int wave, int lane) {
  const int t = wave * 64 + lane;
  #pragma unroll
  for (int i = 0; i < 2; i++) {
    const int row = i * 64 + (t >> 3);
    const int cb  = (t & 7) * 16;                 // byte col 0..112
    const int cbs = cb ^ ((row & 7) << 4);        // 3-bit slot swizzle
    async_ld16(g_rowbase + (long)row * Kstr + (cbs >> 1),
               l_half + i * 4096 + wave * 512);   // wave-uniform linear dest
  }
}

// swizzled fragment read: 8 bf16 at (row r, k..k+7) of a [128][64] half
__device__ __forceinline__ frag_ab ld_frag(const u16* half_base, int r, int k) {
  const int idx = r * 64 + (k ^ ((r & 7) << 3));
  return *reinterpret_cast<const frag_ab*>(half_base + idx);
}

// C = scale * (A @ Bt^T) + bias.  A:[M][K] bf16, Bt:[N][K] bf16 row-major.
// OUT_MODE: 0 fp32 C[M][N]; 1 bf16 C[M][N]; 2 bf16 vT[b][n][l2] (b=row>>11).
// 256x256 tile, BK=64, 8 waves (2M x 4N), 128KB LDS dbuf, 4 phases/K-tile,
// counted vmcnt(4) once per K-tile. z folded into the bijective XCD swizzle.
template<int OUT_MODE>
__device__ __forceinline__ void
gemm256_body(const u16* __restrict__ A, const u16* __restrict__ Bt,
             void* __restrict__ Cout, const float* __restrict__ bias,
             int M, int N, int K, long sA, long sB, long sC, float scale,
             u16* lds)
{
  // ---- bijective XCD swizzle over the FULL grid (z folded in) ----
  const int gx = gridDim.x, gy = gridDim.y, gz = gridDim.z;
  const int nwg = gx * gy * gz;
  const int lin = ((int)blockIdx.z * gy + blockIdx.y) * gx + blockIdx.x;
  const int q8 = nwg >> 3, r8 = nwg & 7;
  const int xcd = lin & 7, idx8 = lin >> 3;
  const int swz = (xcd < r8 ? xcd * (q8 + 1) : r8 * (q8 + 1) + (xcd - r8) * q8) + idx8;
  const int z = swz / (gx * gy);
  const int rem = swz % (gx * gy);
  const int m0 = (rem / gx) * 256;
  const int n0 = (rem % gx) * 256;

  const u16* Ab = A + (long)z * sA;
  const u16* Bb = Bt + (long)z * sB;

  const int tid = threadIdx.x;
  const int wave = tid >> 6, lane = tid & 63;
  const int wm = wave >> 2;        // 0..1 : rows wm*128..+127
  const int wn = wave & 3;         // 0..3 : cols wn*64..+63
  const int ln15 = lane & 15, kof = (lane >> 4) * 8;
  const int rB0 = (wn & 1) * 64;
  const int NT = K >> 6;

  frag_cd acc[8][4];
  #pragma unroll
  for (int i = 0; i < 8; i++)
    #pragma unroll
    for (int j = 0; j < 4; j++)
      acc[i][j] = (frag_cd){0.f, 0.f, 0.f, 0.f};

  // ---- prologue: tile0 all 4 halves + tile1 A-halves; wait 8 oldest ----
  stage_half(Ab + (long)(m0 +   0) * K, K, L(0, 0, 0), wave, lane);
  stage_half(Ab + (long)(m0 + 128) * K, K, L(0, 0, 1), wave, lane);
  stage_half(Bb + (long)(n0 +   0) * K, K, L(0, 1, 0), wave, lane);
  stage_half(Bb + (long)(n0 + 128) * K, K, L(0, 1, 1), wave, lane);
  {
    const int ts = (1 < NT) ? 1 : NT - 1;
    stage_half(Ab + (long)(m0 +   0) * K + ts * 64, K, L(1, 0, 0), wave, lane);
    stage_half(Ab + (long)(m0 + 128) * K + ts * 64, K, L(1, 0, 1), wave, lane);
  }
  WAITV(4);
  BAR();

  for (int t = 0; t < NT; ++t) {
    const int d = t & 1;
    const u16* Al = L(d, 0, wm);
    const u16* Bl = L(d, 1, wn >> 1);
    const int tb = (t + 1 < NT) ? t + 1 : NT - 1;   // B-staging source tile
    const int ta = (t + 2 < NT) ? t + 2 : NT - 1;   // A-staging source tile

    frag_ab bf[4][2], af[8][2];

    // ---- PHASE A: read B frags (8) + A quad0 (4); stage B-h0 of t+1 ----
    #pragma unroll
    for (int bn = 0; bn < 4; ++bn)
      #pragma unroll
      for (int kk = 0; kk < 2; ++kk)
        bf[bn][kk] = ld_frag(Bl, rB0 + bn * 16 + ln15, kk * 32 + kof);
    #pragma unroll
    for (int am = 0; am < 2; ++am)
      #pragma unroll
      for (int kk = 0; kk < 2; ++kk)
        af[am][kk] = ld_frag(Al, am * 16 + ln15, kk * 32 + kof);
    stage_half(Bb + (long)(n0 + 0) * K + tb * 64, K, L(d ^ 1, 1, 0), wave, lane);
    BAR();
    __builtin_amdgcn_s_setprio(1);
    #pragma unroll
    for (int am = 0; am < 2; ++am)
      #pragma unroll
      for (int bn = 0; bn < 4; ++bn)
        #pragma unroll
        for (int kk = 0; kk < 2; ++kk)
          acc[am][bn] = __builtin_amdgcn_mfma_f32_16x16x32_bf16(af[am][kk], bf[bn][kk], acc[am][bn], 0, 0, 0);
    __builtin_amdgcn_s_setprio(0);
    BAR();

    // ---- PHASE B: read A quads 1-3 (12); stage B-h1 of t+1 ----
    #pragma unroll
    for (int am = 2; am < 8; ++am)
      #pragma unroll
      for (int kk = 0; kk < 2; ++kk)
        af[am][kk] = ld_frag(Al, am * 16 + ln15, kk * 32 + kof);
    stage_half(Bb + (long)(n0 + 128) * K + tb * 64, K, L(d ^ 1, 1, 1), wave, lane);
    BAR();
    __builtin_amdgcn_s_setprio(1);
    #pragma unroll
    for (int am = 2; am < 4; ++am)
      #pragma unroll
      for (int bn = 0; bn < 4; ++bn)
        #pragma unroll
        for (int kk = 0; kk < 2; ++kk)
          acc[am][bn] = __builtin_amdgcn_mfma_f32_16x16x32_bf16(af[am][kk], bf[bn][kk], acc[am][bn], 0, 0, 0);
    __builtin_amdgcn_s_setprio(0);
    BAR();

    // ---- PHASE C: stage A-h0 of t+2 (into dbuf d, reads done) ----
    stage_half(Ab + (long)(m0 + 0) * K + ta * 64, K, L(d, 0, 0), wave, lane);
    BAR();
    __builtin_amdgcn_s_setprio(1);
    #pragma unroll
    for (int am = 4; am < 6; ++am)
      #pragma unroll
      for (int bn = 0; bn < 4; ++bn)
        #pragma unroll
        for (int kk = 0; kk < 2; ++kk)
          acc[am][bn] = __builtin_amdgcn_mfma_f32_16x16x32_bf16(af[am][kk], bf[bn][kk], acc[am][bn], 0, 0, 0);
    __builtin_amdgcn_s_setprio(0);
    BAR();

    // ---- PHASE D: stage A-h1 of t+2; counted vmcnt(4); tile barrier ----
    stage_half(Ab + (long)(m0 + 128) * K + ta * 64, K, L(d, 0, 1), wave, lane);
    BAR();
    __builtin_amdgcn_s_setprio(1);
    #pragma unroll
    for (int am = 6; am < 8; ++am)
      #pragma unroll
      for (int bn = 0; bn < 4; ++bn)
        #pragma unroll
        for (int kk = 0; kk < 2; ++kk)
          acc[am][bn] = __builtin_amdgcn_mfma_f32_16x16x32_bf16(af[am][kk], bf[bn][kk], acc[am][bn], 0, 0, 0);
    __builtin_amdgcn_s_setprio(0);
    WAITV(4);     // t+1's 4 B-half loads done; 4 newest (t+2 A-halves) in flight
    BAR();
  }

  WAITV(0);       // drain dummy tail prefetches before LDS goes away
  BAR();

  // ---- epilogue: C/D col=lane&15, row=(lane>>4)*4+r (verified mapping) ----
  const int cl = lane & 15;
  const int rb = (lane >> 4) * 4;
  #pragma unroll
  for (int bn = 0; bn < 4; ++bn) {
    const int gcol = n0 + wn * 64 + bn * 16 + cl;
    const float badd = bias ? bias[gcol] : 0.f;
    #pragma unroll
    for (int am = 0; am < 8; ++am) {
      #pragma unroll
      for (int r = 0; r < 4; ++r) {
        const int grow = m0 + wm * 128 + am * 16 + rb + r;
        const float val = acc[am][bn][r] * scale + badd;
        if (OUT_MODE == 0) {
          ((float*)Cout)[(long)z * sC + (long)grow * N + gcol] = val;
        } else if (OUT_MODE == 1) {
          ((u16*)Cout)[(long)z * sC + (long)grow * N + gcol] = f2bf(val);
        } else {
          const int bb = grow >> 11, l2 = grow & 2047;
          ((u16*)Cout)[((long)bb * N + gcol) * 2048 + l2] = f2bf(val);
        }
      }
    }
  }
}

// Distinct names per role so rocprof rows are unambiguous.
__global__ void __launch_bounds__(512, 2)
proj_gemm(const u16* A, const u16* Bt, void* C, const float* bias,
          int M, int N, int K, long sA, long sB, long sC, float scale) {
  __shared__ u16 lds[8 * 8192];
  gemm256_body<1>(A, Bt, C, bias, M, N, K, sA, sB, sC, scale, lds);
}
__global__ void __launch_bounds__(512, 2)
projv_gemm(const u16* A, const u16* Bt, void* C, const float* bias,
           int M, int N, int K, long sA, long sB, long sC, float scale) {
  __shared__ u16 lds[8 * 8192];
  gemm256_body<2>(A, Bt, C, bias, M, N, K, sA, sB, sC, scale, lds);
}
__global__ void __launch_bounds__(512, 2)
qk_gemm(const u16* A, const u16* Bt, void* C, const float* bias,
        int M, int N, int K, long sA, long sB, long sC, float scale) {
  __shared__ u16 lds[8 * 8192];
  gemm256_body<0>(A, Bt, C, bias, M, N, K, sA, sB, sC, scale, lds);
}
__global__ void __launch_bounds__(512, 2)
pv_gemm(const u16* A, const u16* Bt, void* C, const float* bias,
        int M, int N, int K, long sA, long sB, long sC, float scale) {
  __shared__ u16 lds[8 * 8192];
  gemm256_body<0>(A, Bt, C, bias, M, N, K, sA, sB, sC, scale, lds);
}

// softmax over a slab of NB batches: blockIdx.x = global row in [0, NB*2048).
// S, P are slab-local (contiguous); mask batch = row>>11 within the slab.
__global__ void softmax_rows(const float* __restrict__ S, const int* __restrict__ Km,
                             u16* __restrict__ P)
{
  const long row = blockIdx.x;
  const int b = (int)(row >> 11);
  const float* s = S + row * 2048;
  const int* mask = Km + (long)b * 2048;
  u16* p = P + row * 2048;

  const int t = threadIdx.x;
  const int base = t * 8;

  float4 v0 = *reinterpret_cast<const float4*>(s + base);
  float4 v1 = *reinterpret_cast<const float4*>(s + base + 4);
  int4 mA = *reinterpret_cast<const int4*>(mask + base);
  int4 mB = *reinterpret_cast<const int4*>(mask + base + 4);

  float vals[8] = {v0.x, v0.y, v0.z, v0.w, v1.x, v1.y, v1.z, v1.w};
  const int mk[8] = {mA.x, mA.y, mA.z, mA.w, mB.x, mB.y, mB.z, mB.w};

  float mx = -3.0e38f;
  #pragma unroll
  for (int i = 0; i < 8; i++) if (!mk[i]) mx = fmaxf(mx, vals[i]);
  #pragma unroll
  for (int off = 32; off > 0; off >>= 1) mx = fmaxf(mx, __shfl_xor(mx, off));

  __shared__ float redm[4], reds[4];
  const int wave = t >> 6, lane = t & 63;
  if (lane == 0) redm[wave] = mx;
  __syncthreads();
  mx = fmaxf(fmaxf(redm[0], redm[1]), fmaxf(redm[2], redm[3]));

  float e[8]; float sum = 0.f;
  #pragma unroll
  for (int i = 0; i < 8; i++) { e[i] = mk[i] ? 0.f : __expf(vals[i] - mx); sum += e[i]; }
  #pragma unroll
  for (int off = 32; off > 0; off >>= 1) sum += __shfl_xor(sum, off);
  if (lane == 0) reds[wave] = sum;
  __syncthreads();
  sum = reds[0] + reds[1] + reds[2] + reds[3];
  const float inv = 1.f / sum;

  ushort4 o0 = make_ushort4(f2bf(e[0]*inv), f2bf(e[1]*inv), f2bf(e[2]*inv), f2bf(e[3]*inv));
  ushort4 o1 = make_ushort4(f2bf(e[4]*inv), f2bf(e[5]*inv), f2bf(e[6]*inv), f2bf(e[7]*inv));
  *reinterpret_cast<ushort4*>(p + base) = o0;
  *reinterpret_cast<ushort4*>(p + base + 4) = o1;
}

extern "C" void kernel_launch(void* const* d_in, const int* in_sizes, int n_in,
                              void* d_out, int out_size, void* d_ws, size_t ws_size,
                              hipStream_t stream) {
  (void)in_sizes; (void)n_in; (void)out_size;

  const float* Qin  = (const float*)d_in[0];
  const float* Kin  = (const float*)d_in[1];
  const float* Vin  = (const float*)d_in[2];
  const int*   Kmask = (const int*)d_in[3];
  const float* Wq = (const float*)d_in[4];
  const float* bq = (const float*)d_in[5];
  const float* Wk = (const float*)d_in[6];
  const float* bk = (const float*)d_in[7];
  const float* Wv = (const float*)d_in[8];
  const float* bv = (const float*)d_in[9];

  char* ws = (char*)d_ws;
  const size_t MB = 1024UL * 1024UL;
  const long NQKV = 8L * 2048 * 1024;
  const long NW = 1024L * 1024;
  const dim3 blk(256);
  const dim3 gblk(512);
  const float rs = 0.03125f;  // 1/sqrt(1024)

  if (ws_size >= 226 * MB) {
    // ---- 226 MB layout: 4-batch S slab -> QK at full-GPU occupancy ----
    //   [0,32)    qb   [32,64) kb   [64,96) vT
    //   [96,160)  P (head doubles as Xb during projections)
    //   [160,224) S fp32 [4][2048][2048]
    //   [224,226) Wb
    u16*  qb = (u16*)(ws);
    u16*  kb = (u16*)(ws + 32 * MB);
    u16*  vT = (u16*)(ws + 64 * MB);
    u16*  P  = (u16*)(ws + 96 * MB);
    u16*  Xb = (u16*)(ws + 96 * MB);
    float* S = (float*)(ws + 160 * MB);
    u16*  Wb = (u16*)(ws + 224 * MB);

    cvt_f32_bf16<<<dim3(NQKV / 1024), blk, 0, stream>>>(Qin, Xb, NQKV);
    cvt_f32_bf16<<<dim3(NW / 1024), blk, 0, stream>>>(Wq, Wb, NW);
    proj_gemm<<<dim3(4, 64, 1), gblk, 0, stream>>>(Xb, Wb, qb, bq,
        16384, 1024, 1024, 0, 0, 0, 1.f);

    cvt_f32_bf16<<<dim3(NQKV / 1024), blk, 0, stream>>>(Kin, Xb, NQKV);
    cvt_f32_bf16<<<dim3(NW / 1024), blk, 0, stream>>>(Wk, Wb, NW);
    proj_gemm<<<dim3(4, 64, 1), gblk, 0, stream>>>(Xb, Wb, kb, bk,
        16384, 1024, 1024, 0, 0, 0, 1.f);

    cvt_f32_bf16<<<dim3(NQKV / 1024), blk, 0, stream>>>(Vin, Xb, NQKV);
    cvt_f32_bf16<<<dim3(NW / 1024), blk, 0, stream>>>(Wv, Wb, NW);
    projv_gemm<<<dim3(4, 64, 1), gblk, 0, stream>>>(Xb, Wb, vT, bv,
        16384, 1024, 1024, 0, 0, 0, 1.f);

    // QK + softmax, 4 batches per pass (grid 256 blocks = full GPU)
    for (int h = 0; h < 2; h++) {
      const u16* qbH = qb + (long)(4 * h) * 2048 * 1024;
      const u16* kbH = kb + (long)(4 * h) * 2048 * 1024;
      qk_gemm<<<dim3(8, 8, 4), gblk, 0, stream>>>(qbH, kbH, S, nullptr,
          2048, 2048, 1024, 2048L * 1024, 2048L * 1024, 2048L * 2048, rs);
      softmax_rows<<<dim3(8192), blk, 0, stream>>>(
          S, Kmask + (long)(4 * h) * 2048, P + (long)(4 * h) * 2048 * 2048);
    }

    pv_gemm<<<dim3(4, 8, 8), gblk, 0, stream>>>(P, vT, d_out, nullptr,
        2048, 1024, 2048, 2048L * 2048, 1024L * 2048, 2048L * 1024, 1.f);
  } else if (ws_size >= 194 * MB) {
    // ---- 194 MB layout (round-4 schedule, new kernels) ----
    u16*  qb = (u16*)(ws);
    u16*  kb = (u16*)(ws + 32 * MB);
    u16*  vT = (u16*)(ws + 64 * MB);
    u16*  P  = (u16*)(ws + 96 * MB);
    u16*  Xb = (u16*)(ws + 96 * MB);
    float* S = (float*)(ws + 160 * MB);
    u16*  Wb = (u16*)(ws + 192 * MB);

    cvt_f32_bf16<<<dim3(NQKV / 1024), blk, 0, stream>>>(Qin, Xb, NQKV);
    cvt_f32_bf16<<<dim3(NW / 1024), blk, 0, stream>>>(Wq, Wb, NW);
    proj_gemm<<<dim3(4, 64, 1), gblk, 0, stream>>>(Xb, Wb, qb, bq,
        16384, 1024, 1024, 0, 0, 0, 1.f);

    cvt_f32_bf16<<<dim3(NQKV / 1024), blk, 0, stream>>>(Kin, Xb, NQKV);
    cvt_f32_bf16<<<dim3(NW / 1024), blk, 0, stream>>>(Wk, Wb, NW);
    proj_gemm<<<dim3(4, 64, 1), gblk, 0, stream>>>(Xb, Wb, kb, bk,
        16384, 1024, 1024, 0, 0, 0, 1.f);

    cvt_f32_bf16<<<dim3(NQKV / 1024), blk, 0, stream>>>(Vin, Xb, NQKV);
    cvt_f32_bf16<<<dim3(NW / 1024), blk, 0, stream>>>(Wv, Wb, NW);
    projv_gemm<<<dim3(4, 64, 1), gblk, 0, stream>>>(Xb, Wb, vT, bv,
        16384, 1024, 1024, 0, 0, 0, 1.f);

    for (int p = 0; p < 4; p++) {
      const u16* qbP = qb + (long)(2 * p) * 2048 * 1024;
      const u16* kbP = kb + (long)(2 * p) * 2048 * 1024;
      qk_gemm<<<dim3(8, 8, 2), gblk, 0, stream>>>(qbP, kbP, S, nullptr,
          2048, 2048, 1024, 2048L * 1024, 2048L * 1024, 2048L * 2048, rs);
      softmax_rows<<<dim3(4096), blk, 0, stream>>>(
          S, Kmask + (long)(2 * p) * 2048, P + (long)(2 * p) * 2048 * 2048);
    }

    pv_gemm<<<dim3(4, 8, 8), gblk, 0, stream>>>(P, vT, d_out, nullptr,
        2048, 1024, 2048, 2048L * 2048, 1024L * 2048, 2048L * 1024, 1.f);
  } else {
    // ---- minimal 130 MB fallback: per-batch S/P streaming ----
    u16*  qb = (u16*)(ws);
    u16*  kb = (u16*)(ws + 32 * MB);
    u16*  vT = (u16*)(ws + 64 * MB);
    u16*  Xb = (u16*)(ws + 96 * MB);
    float* S = (float*)(ws + 96 * MB);
    u16*  P  = (u16*)(ws + 112 * MB);
    u16*  Wb = (u16*)(ws + 128 * MB);

    cvt_f32_bf16<<<dim3(NQKV / 1024), blk, 0, stream>>>(Qin, Xb, NQKV);
    cvt_f32_bf16<<<dim3(NW / 1024), blk, 0, stream>>>(Wq, Wb, NW);
    proj_gemm<<<dim3(4, 64, 1), gblk, 0, stream>>>(Xb, Wb, qb, bq,
        16384, 1024, 1024, 0, 0, 0, 1.f);

    cvt_f32_bf16<<<dim3(NQKV / 1024), blk, 0, stream>>>(Kin, Xb, NQKV);
    cvt_f32_bf16<<<dim3(NW / 1024), blk, 0, stream>>>(Wk, Wb, NW);
    proj_gemm<<<dim3(4, 64, 1), gblk, 0, stream>>>(Xb, Wb, kb, bk,
        16384, 1024, 1024, 0, 0, 0, 1.f);

    cvt_f32_bf16<<<dim3(NQKV / 1024), blk, 0, stream>>>(Vin, Xb, NQKV);
    cvt_f32_bf16<<<dim3(NW / 1024), blk, 0, stream>>>(Wv, Wb, NW);
    projv_gemm<<<dim3(4, 64, 1), gblk, 0, stream>>>(Xb, Wb, vT, bv,
        16384, 1024, 1024, 0, 0, 0, 1.f);

    for (int b = 0; b < 8; b++) {
      const u16* qbB = qb + (long)b * 2048 * 1024;
      const u16* kbB = kb + (long)b * 2048 * 1024;
      const u16* vTB = vT + (long)b * 1024 * 2048;
      float* outB = (float*)d_out + (long)b * 2048 * 1024;

      qk_gemm<<<dim3(8, 8, 1), gblk, 0, stream>>>(qbB, kbB, S, nullptr,
          2048, 2048, 1024, 0, 0, 0, rs);
      softmax_rows<<<dim3(2048), blk, 0, stream>>>(S, Kmask + (long)b * 2048, P);
      pv_gemm<<<dim3(4, 8, 1), gblk, 0, stream>>>(P, vTB, outB, nullptr,
          2048, 1024, 2048, 0, 0, 0, 1.f);
    }
  }
}

// Round 6
// 383.069 us; speedup vs baseline: 2.1632x; 1.0148x over previous
//
#include <hip/hip_runtime.h>

// ---------------------------------------------------------------------------
// ScaleDotProductAttention: q=Q@Wq^T+bq; k=K@Wk^T+bk; v=V@Wv^T+bv
// S = q@k^T/32 (mask==1 -> -inf), P=softmax(S), out = P@v
// B=8, L1=L2=2048, D=E=1024. bf16 MFMA 16x16x32, fp32 accum.
// Round 6: m201-faithful phase schedule — ds_reads spread 12/4/4/4 (was
// 12/12/0/0, LDS pipe bunching), staging lead extended (A: 4 phases,
// B: 5-7 phases, was 2-3), one vmcnt(4) per K-tile at q3-end.
// ---------------------------------------------------------------------------

using u16 = unsigned short;
using frag_ab = __attribute__((ext_vector_type(8))) short;   // 8 bf16 (4 VGPRs)
using frag_cd = __attribute__((ext_vector_type(4))) float;   // 4 fp32

#define BAR() asm volatile("s_barrier" ::: "memory")
#define WAITV(n) asm volatile("s_waitcnt vmcnt(" #n ")" ::: "memory")
#define L(d, ab, h) (lds + (((d) * 4) + ((ab) * 2) + (h)) * 8192)

__device__ __forceinline__ u16 f2bf(float f) {
  union { float f; unsigned u; } c; c.f = f;
  unsigned u = c.u;
  return (u16)((u + 0x7FFFu + ((u >> 16) & 1u)) >> 16);   // RNE
}

__device__ __forceinline__ void async_ld16(const void* g, void* l) {
  __builtin_amdgcn_global_load_lds(
      (const __attribute__((address_space(1))) unsigned*)g,
      (__attribute__((address_space(3))) unsigned*)l, 16, 0, 0);
}

// fp32 -> bf16 bits, 4 elems/thread
__global__ void cvt_f32_bf16(const float* __restrict__ in, u16* __restrict__ out, long n) {
  long i = ((long)blockIdx.x * 256 + threadIdx.x) * 4;
  if (i >= n) return;
  float4 v = *reinterpret_cast<const float4*>(in + i);
  ushort4 o = make_ushort4(f2bf(v.x), f2bf(v.y), f2bf(v.z), f2bf(v.w));
  *reinterpret_cast<ushort4*>(out + i) = o;
}

// Stage one 128x64 bf16 half-tile. LDS dest linear (global_load_lds rule);
// 3-bit XOR swizzle (row&7)<<4 pre-applied to the GLOBAL source 16B-slot
// (involution; ld_frag applies the same XOR).  2 issues x 512 thr x 16B.
__device__ __forceinline__ void stage_half(const u16* __restrict__ g_rowbase,
                                           long Kstr, u16* l_half,
                                           int wave, int lane) {
  const int t = wave * 64 + lane;
  #pragma unroll
  for (int i = 0; i < 2; i++) {
    const int row = i * 64 + (t >> 3);
    const int cb  = (t & 7) * 16;                 // byte col 0..112
    const int cbs = cb ^ ((row & 7) << 4);        // 3-bit slot swizzle
    async_ld16(g_rowbase + (long)row * Kstr + (cbs >> 1),
               l_half + i * 4096 + wave * 512);   // wave-uniform linear dest
  }
}

// swizzled fragment read: 8 bf16 at (row r, k..k+7) of a [128][64] half
__device__ __forceinline__ frag_ab ld_frag(const u16* half_base, int r, int k) {
  const int idx = r * 64 + (k ^ ((r & 7) << 3));
  return *reinterpret_cast<const frag_ab*>(half_base + idx);
}

// C = scale * (A @ Bt^T) + bias.  A:[M][K] bf16, Bt:[N][K] bf16 row-major.
// OUT_MODE: 0 fp32 C[M][N]; 1 bf16 C[M][N]; 2 bf16 vT[b][n][l2] (b=row>>11).
// 256x256 tile, BK=64, 8 waves (2M x 4N), 128KB LDS dbuf.
// Phase schedule per K-tile t (dbuf d = t&1):
//   q0: reads bf(t)[8]+af01[4]; stage Ah0,Ah1(t+1)->d^1[0]; BAR; mfma am0-1; BAR
//   q1: reads af23;             stage Bh0(t+2)->d[1][0];    BAR; mfma am2-3; BAR
//   q2: reads af45;             stage Bh1(t+2)->d[1][1];    BAR; mfma am4-5; BAR
//   q3: reads af67;                                         BAR; mfma am6-7;
//       WAITV(4) (drain A(t+1), keep B(t+2) in flight); BAR
template<int OUT_MODE>
__device__ __forceinline__ void
gemm256_body(const u16* __restrict__ A, const u16* __restrict__ Bt,
             void* __restrict__ Cout, const float* __restrict__ bias,
             int M, int N, int K, long sA, long sB, long sC, float scale,
             u16* lds)
{
  // ---- bijective XCD swizzle over the FULL grid (z folded in) ----
  const int gx = gridDim.x, gy = gridDim.y, gz = gridDim.z;
  const int nwg = gx * gy * gz;
  const int lin = ((int)blockIdx.z * gy + blockIdx.y) * gx + blockIdx.x;
  const int q8 = nwg >> 3, r8 = nwg & 7;
  const int xcd = lin & 7, idx8 = lin >> 3;
  const int swz = (xcd < r8 ? xcd * (q8 + 1) : r8 * (q8 + 1) + (xcd - r8) * q8) + idx8;
  const int z = swz / (gx * gy);
  const int rem = swz % (gx * gy);
  const int m0 = (rem / gx) * 256;
  const int n0 = (rem % gx) * 256;

  const u16* Ab = A + (long)z * sA;
  const u16* Bb = Bt + (long)z * sB;

  const int tid = threadIdx.x;
  const int wave = tid >> 6, lane = tid & 63;
  const int wm = wave >> 2;        // 0..1 : rows wm*128..+127
  const int wn = wave & 3;         // 0..3 : cols wn*64..+63
  const int ln15 = lane & 15, kof = (lane >> 4) * 8;
  const int rB0 = (wn & 1) * 64;
  const int NT = K >> 6;

  frag_cd acc[8][4];
  #pragma unroll
  for (int i = 0; i < 8; i++)
    #pragma unroll
    for (int j = 0; j < 4; j++)
      acc[i][j] = (frag_cd){0.f, 0.f, 0.f, 0.f};

  // ---- prologue: A(0), B(0) -> dbuf0; B(1) -> dbuf1; drain A0/B0 ----
  stage_half(Ab + (long)(m0 +   0) * K, K, L(0, 0, 0), wave, lane);
  stage_half(Ab + (long)(m0 + 128) * K, K, L(0, 0, 1), wave, lane);
  stage_half(Bb + (long)(n0 +   0) * K, K, L(0, 1, 0), wave, lane);
  stage_half(Bb + (long)(n0 + 128) * K, K, L(0, 1, 1), wave, lane);
  {
    const int t1 = (1 < NT) ? 1 : 0;
    stage_half(Bb + (long)(n0 +   0) * K + t1 * 64, K, L(1, 1, 0), wave, lane);
    stage_half(Bb + (long)(n0 + 128) * K + t1 * 64, K, L(1, 1, 1), wave, lane);
  }
  WAITV(4);   // A(0),B(0) landed; B(1) (4 newest) still in flight
  BAR();

  for (int t = 0; t < NT; ++t) {
    const int d = t & 1;
    const u16* Al = L(d, 0, wm);
    const u16* Bl = L(d, 1, wn >> 1);
    const int tA = (t + 1 < NT) ? t + 1 : NT - 1;   // A staging source tile
    const int tB = (t + 2 < NT) ? t + 2 : NT - 1;   // B staging source tile

    frag_ab bf[4][2], af[2][2];

    // ---------------- q0: 12 reads; stage A(t+1); mfma am0-1 ----------------
    #pragma unroll
    for (int bn = 0; bn < 4; ++bn)
      #pragma unroll
      for (int kk = 0; kk < 2; ++kk)
        bf[bn][kk] = ld_frag(Bl, rB0 + bn * 16 + ln15, kk * 32 + kof);
    #pragma unroll
    for (int am = 0; am < 2; ++am)
      #pragma unroll
      for (int kk = 0; kk < 2; ++kk)
        af[am][kk] = ld_frag(Al, am * 16 + ln15, kk * 32 + kof);
    stage_half(Ab + (long)(m0 +   0) * K + tA * 64, K, L(d ^ 1, 0, 0), wave, lane);
    stage_half(Ab + (long)(m0 + 128) * K + tA * 64, K, L(d ^ 1, 0, 1), wave, lane);
    BAR();
    __builtin_amdgcn_s_setprio(1);
    #pragma unroll
    for (int am = 0; am < 2; ++am)
      #pragma unroll
      for (int bn = 0; bn < 4; ++bn)
        #pragma unroll
        for (int kk = 0; kk < 2; ++kk)
          acc[am][bn] = __builtin_amdgcn_mfma_f32_16x16x32_bf16(af[am][kk], bf[bn][kk], acc[am][bn], 0, 0, 0);
    __builtin_amdgcn_s_setprio(0);
    BAR();

    // ---------------- q1: 4 reads; stage Bh0(t+2); mfma am2-3 ---------------
    #pragma unroll
    for (int am = 0; am < 2; ++am)
      #pragma unroll
      for (int kk = 0; kk < 2; ++kk)
        af[am][kk] = ld_frag(Al, (2 + am) * 16 + ln15, kk * 32 + kof);
    stage_half(Bb + (long)(n0 + 0) * K + tB * 64, K, L(d, 1, 0), wave, lane);
    BAR();
    __builtin_amdgcn_s_setprio(1);
    #pragma unroll
    for (int am = 0; am < 2; ++am)
      #pragma unroll
      for (int bn = 0; bn < 4; ++bn)
        #pragma unroll
        for (int kk = 0; kk < 2; ++kk)
          acc[2 + am][bn] = __builtin_amdgcn_mfma_f32_16x16x32_bf16(af[am][kk], bf[bn][kk], acc[2 + am][bn], 0, 0, 0);
    __builtin_amdgcn_s_setprio(0);
    BAR();

    // ---------------- q2: 4 reads; stage Bh1(t+2); mfma am4-5 ---------------
    #pragma unroll
    for (int am = 0; am < 2; ++am)
      #pragma unroll
      for (int kk = 0; kk < 2; ++kk)
        af[am][kk] = ld_frag(Al, (4 + am) * 16 + ln15, kk * 32 + kof);
    stage_half(Bb + (long)(n0 + 128) * K + tB * 64, K, L(d, 1, 1), wave, lane);
    BAR();
    __builtin_amdgcn_s_setprio(1);
    #pragma unroll
    for (int am = 0; am < 2; ++am)
      #pragma unroll
      for (int bn = 0; bn < 4; ++bn)
        #pragma unroll
        for (int kk = 0; kk < 2; ++kk)
          acc[4 + am][bn] = __builtin_amdgcn_mfma_f32_16x16x32_bf16(af[am][kk], bf[bn][kk], acc[4 + am][bn], 0, 0, 0);
    __builtin_amdgcn_s_setprio(0);
    BAR();

    // ---------------- q3: 4 reads; mfma am6-7; per-tile vmcnt(4) ------------
    #pragma unroll
    for (int am = 0; am < 2; ++am)
      #pragma unroll
      for (int kk = 0; kk < 2; ++kk)
        af[am][kk] = ld_frag(Al, (6 + am) * 16 + ln15, kk * 32 + kof);
    BAR();
    __builtin_amdgcn_s_setprio(1);
    #pragma unroll
    for (int am = 0; am < 2; ++am)
      #pragma unroll
      for (int bn = 0; bn < 4; ++bn)
        #pragma unroll
        for (int kk = 0; kk < 2; ++kk)
          acc[6 + am][bn] = __builtin_amdgcn_mfma_f32_16x16x32_bf16(af[am][kk], bf[bn][kk], acc[6 + am][bn], 0, 0, 0);
    __builtin_amdgcn_s_setprio(0);
    WAITV(4);   // drain A(t+1) (4 oldest); B(t+2) (4 newest) stays in flight
    BAR();
  }

  WAITV(0);     // drain tail dummy prefetches before LDS goes away
  BAR();

  // ---- epilogue: C/D col=lane&15, row=(lane>>4)*4+r (verified mapping) ----
  const int cl = lane & 15;
  const int rb = (lane >> 4) * 4;
  #pragma unroll
  for (int bn = 0; bn < 4; ++bn) {
    const int gcol = n0 + wn * 64 + bn * 16 + cl;
    const float badd = bias ? bias[gcol] : 0.f;
    #pragma unroll
    for (int am = 0; am < 8; ++am) {
      #pragma unroll
      for (int r = 0; r < 4; ++r) {
        const int grow = m0 + wm * 128 + am * 16 + rb + r;
        const float val = acc[am][bn][r] * scale + badd;
        if (OUT_MODE == 0) {
          ((float*)Cout)[(long)z * sC + (long)grow * N + gcol] = val;
        } else if (OUT_MODE == 1) {
          ((u16*)Cout)[(long)z * sC + (long)grow * N + gcol] = f2bf(val);
        } else {
          const int bb = grow >> 11, l2 = grow & 2047;
          ((u16*)Cout)[((long)bb * N + gcol) * 2048 + l2] = f2bf(val);
        }
      }
    }
  }
}

// Distinct names per role so rocprof rows are unambiguous.
__global__ void __launch_bounds__(512, 2)
proj_gemm(const u16* A, const u16* Bt, void* C, const float* bias,
          int M, int N, int K, long sA, long sB, long sC, float scale) {
  __shared__ u16 lds[8 * 8192];
  gemm256_body<1>(A, Bt, C, bias, M, N, K, sA, sB, sC, scale, lds);
}
__global__ void __launch_bounds__(512, 2)
projv_gemm(const u16* A, const u16* Bt, void* C, const float* bias,
           int M, int N, int K, long sA, long sB, long sC, float scale) {
  __shared__ u16 lds[8 * 8192];
  gemm256_body<2>(A, Bt, C, bias, M, N, K, sA, sB, sC, scale, lds);
}
__global__ void __launch_bounds__(512, 2)
qk_gemm(const u16* A, const u16* Bt, void* C, const float* bias,
        int M, int N, int K, long sA, long sB, long sC, float scale) {
  __shared__ u16 lds[8 * 8192];
  gemm256_body<0>(A, Bt, C, bias, M, N, K, sA, sB, sC, scale, lds);
}
__global__ void __launch_bounds__(512, 2)
pv_gemm(const u16* A, const u16* Bt, void* C, const float* bias,
        int M, int N, int K, long sA, long sB, long sC, float scale) {
  __shared__ u16 lds[8 * 8192];
  gemm256_body<0>(A, Bt, C, bias, M, N, K, sA, sB, sC, scale, lds);
}

// softmax over a slab: blockIdx.x = row in [0, NB*2048); mask batch = row>>11
__global__ void softmax_rows(const float* __restrict__ S, const int* __restrict__ Km,
                             u16* __restrict__ P)
{
  const long row = blockIdx.x;
  const int b = (int)(row >> 11);
  const float* s = S + row * 2048;
  const int* mask = Km + (long)b * 2048;
  u16* p = P + row * 2048;

  const int t = threadIdx.x;
  const int base = t * 8;

  float4 v0 = *reinterpret_cast<const float4*>(s + base);
  float4 v1 = *reinterpret_cast<const float4*>(s + base + 4);
  int4 mA = *reinterpret_cast<const int4*>(mask + base);
  int4 mB = *reinterpret_cast<const int4*>(mask + base + 4);

  float vals[8] = {v0.x, v0.y, v0.z, v0.w, v1.x, v1.y, v1.z, v1.w};
  const int mk[8] = {mA.x, mA.y, mA.z, mA.w, mB.x, mB.y, mB.z, mB.w};

  float mx = -3.0e38f;
  #pragma unroll
  for (int i = 0; i < 8; i++) if (!mk[i]) mx = fmaxf(mx, vals[i]);
  #pragma unroll
  for (int off = 32; off > 0; off >>= 1) mx = fmaxf(mx, __shfl_xor(mx, off));

  __shared__ float redm[4], reds[4];
  const int wave = t >> 6, lane = t & 63;
  if (lane == 0) redm[wave] = mx;
  __syncthreads();
  mx = fmaxf(fmaxf(redm[0], redm[1]), fmaxf(redm[2], redm[3]));

  float e[8]; float sum = 0.f;
  #pragma unroll
  for (int i = 0; i < 8; i++) { e[i] = mk[i] ? 0.f : __expf(vals[i] - mx); sum += e[i]; }
  #pragma unroll
  for (int off = 32; off > 0; off >>= 1) sum += __shfl_xor(sum, off);
  if (lane == 0) reds[wave] = sum;
  __syncthreads();
  sum = reds[0] + reds[1] + reds[2] + reds[3];
  const float inv = 1.f / sum;

  ushort4 o0 = make_ushort4(f2bf(e[0]*inv), f2bf(e[1]*inv), f2bf(e[2]*inv), f2bf(e[3]*inv));
  ushort4 o1 = make_ushort4(f2bf(e[4]*inv), f2bf(e[5]*inv), f2bf(e[6]*inv), f2bf(e[7]*inv));
  *reinterpret_cast<ushort4*>(p + base) = o0;
  *reinterpret_cast<ushort4*>(p + base + 4) = o1;
}

extern "C" void kernel_launch(void* const* d_in, const int* in_sizes, int n_in,
                              void* d_out, int out_size, void* d_ws, size_t ws_size,
                              hipStream_t stream) {
  (void)in_sizes; (void)n_in; (void)out_size;

  const float* Qin  = (const float*)d_in[0];
  const float* Kin  = (const float*)d_in[1];
  const float* Vin  = (const float*)d_in[2];
  const int*   Kmask = (const int*)d_in[3];
  const float* Wq = (const float*)d_in[4];
  const float* bq = (const float*)d_in[5];
  const float* Wk = (const float*)d_in[6];
  const float* bk = (const float*)d_in[7];
  const float* Wv = (const float*)d_in[8];
  const float* bv = (const float*)d_in[9];

  char* ws = (char*)d_ws;
  const size_t MB = 1024UL * 1024UL;
  const long NQKV = 8L * 2048 * 1024;
  const long NW = 1024L * 1024;
  const dim3 blk(256);
  const dim3 gblk(512);
  const float rs = 0.03125f;  // 1/sqrt(1024)

  if (ws_size >= 226 * MB) {
    // ---- 226 MB layout: 4-batch S slab -> QK at full-GPU occupancy ----
    u16*  qb = (u16*)(ws);
    u16*  kb = (u16*)(ws + 32 * MB);
    u16*  vT = (u16*)(ws + 64 * MB);
    u16*  P  = (u16*)(ws + 96 * MB);
    u16*  Xb = (u16*)(ws + 96 * MB);
    float* S = (float*)(ws + 160 * MB);
    u16*  Wb = (u16*)(ws + 224 * MB);

    cvt_f32_bf16<<<dim3(NQKV / 1024), blk, 0, stream>>>(Qin, Xb, NQKV);
    cvt_f32_bf16<<<dim3(NW / 1024), blk, 0, stream>>>(Wq, Wb, NW);
    proj_gemm<<<dim3(4, 64, 1), gblk, 0, stream>>>(Xb, Wb, qb, bq,
        16384, 1024, 1024, 0, 0, 0, 1.f);

    cvt_f32_bf16<<<dim3(NQKV / 1024), blk, 0, stream>>>(Kin, Xb, NQKV);
    cvt_f32_bf16<<<dim3(NW / 1024), blk, 0, stream>>>(Wk, Wb, NW);
    proj_gemm<<<dim3(4, 64, 1), gblk, 0, stream>>>(Xb, Wb, kb, bk,
        16384, 1024, 1024, 0, 0, 0, 1.f);

    cvt_f32_bf16<<<dim3(NQKV / 1024), blk, 0, stream>>>(Vin, Xb, NQKV);
    cvt_f32_bf16<<<dim3(NW / 1024), blk, 0, stream>>>(Wv, Wb, NW);
    projv_gemm<<<dim3(4, 64, 1), gblk, 0, stream>>>(Xb, Wb, vT, bv,
        16384, 1024, 1024, 0, 0, 0, 1.f);

    for (int h = 0; h < 2; h++) {
      const u16* qbH = qb + (long)(4 * h) * 2048 * 1024;
      const u16* kbH = kb + (long)(4 * h) * 2048 * 1024;
      qk_gemm<<<dim3(8, 8, 4), gblk, 0, stream>>>(qbH, kbH, S, nullptr,
          2048, 2048, 1024, 2048L * 1024, 2048L * 1024, 2048L * 2048, rs);
      softmax_rows<<<dim3(8192), blk, 0, stream>>>(
          S, Kmask + (long)(4 * h) * 2048, P + (long)(4 * h) * 2048 * 2048);
    }

    pv_gemm<<<dim3(4, 8, 8), gblk, 0, stream>>>(P, vT, d_out, nullptr,
        2048, 1024, 2048, 2048L * 2048, 1024L * 2048, 2048L * 1024, 1.f);
  } else if (ws_size >= 194 * MB) {
    // ---- 194 MB layout ----
    u16*  qb = (u16*)(ws);
    u16*  kb = (u16*)(ws + 32 * MB);
    u16*  vT = (u16*)(ws + 64 * MB);
    u16*  P  = (u16*)(ws + 96 * MB);
    u16*  Xb = (u16*)(ws + 96 * MB);
    float* S = (float*)(ws + 160 * MB);
    u16*  Wb = (u16*)(ws + 192 * MB);

    cvt_f32_bf16<<<dim3(NQKV / 1024), blk, 0, stream>>>(Qin, Xb, NQKV);
    cvt_f32_bf16<<<dim3(NW / 1024), blk, 0, stream>>>(Wq, Wb, NW);
    proj_gemm<<<dim3(4, 64, 1), gblk, 0, stream>>>(Xb, Wb, qb, bq,
        16384, 1024, 1024, 0, 0, 0, 1.f);

    cvt_f32_bf16<<<dim3(NQKV / 1024), blk, 0, stream>>>(Kin, Xb, NQKV);
    cvt_f32_bf16<<<dim3(NW / 1024), blk, 0, stream>>>(Wk, Wb, NW);
    proj_gemm<<<dim3(4, 64, 1), gblk, 0, stream>>>(Xb, Wb, kb, bk,
        16384, 1024, 1024, 0, 0, 0, 1.f);

    cvt_f32_bf16<<<dim3(NQKV / 1024), blk, 0, stream>>>(Vin, Xb, NQKV);
    cvt_f32_bf16<<<dim3(NW / 1024), blk, 0, stream>>>(Wv, Wb, NW);
    projv_gemm<<<dim3(4, 64, 1), gblk, 0, stream>>>(Xb, Wb, vT, bv,
        16384, 1024, 1024, 0, 0, 0, 1.f);

    for (int p = 0; p < 4; p++) {
      const u16* qbP = qb + (long)(2 * p) * 2048 * 1024;
      const u16* kbP = kb + (long)(2 * p) * 2048 * 1024;
      qk_gemm<<<dim3(8, 8, 2), gblk, 0, stream>>>(qbP, kbP, S, nullptr,
          2048, 2048, 1024, 2048L * 1024, 2048L * 1024, 2048L * 2048, rs);
      softmax_rows<<<dim3(4096), blk, 0, stream>>>(
          S, Kmask + (long)(2 * p) * 2048, P + (long)(2 * p) * 2048 * 2048);
    }

    pv_gemm<<<dim3(4, 8, 8), gblk, 0, stream>>>(P, vT, d_out, nullptr,
        2048, 1024, 2048, 2048L * 2048, 1024L * 2048, 2048L * 1024, 1.f);
  } else {
    // ---- minimal 130 MB fallback: per-batch S/P streaming ----
    u16*  qb = (u16*)(ws);
    u16*  kb = (u16*)(ws + 32 * MB);
    u16*  vT = (u16*)(ws + 64 * MB);
    u16*  Xb = (u16*)(ws + 96 * MB);
    float* S = (float*)(ws + 96 * MB);
    u16*  P  = (u16*)(ws + 112 * MB);
    u16*  Wb = (u16*)(ws + 128 * MB);

    cvt_f32_bf16<<<dim3(NQKV / 1024), blk, 0, stream>>>(Qin, Xb, NQKV);
    cvt_f32_bf16<<<dim3(NW / 1024), blk, 0, stream>>>(Wq, Wb, NW);
    proj_gemm<<<dim3(4, 64, 1), gblk, 0, stream>>>(Xb, Wb, qb, bq,
        16384, 1024, 1024, 0, 0, 0, 1.f);

    cvt_f32_bf16<<<dim3(NQKV / 1024), blk, 0, stream>>>(Kin, Xb, NQKV);
    cvt_f32_bf16<<<dim3(NW / 1024), blk, 0, stream>>>(Wk, Wb, NW);
    proj_gemm<<<dim3(4, 64, 1), gblk, 0, stream>>>(Xb, Wb, kb, bk,
        16384, 1024, 1024, 0, 0, 0, 1.f);

    cvt_f32_bf16<<<dim3(NQKV / 1024), blk, 0, stream>>>(Vin, Xb, NQKV);
    cvt_f32_bf16<<<dim3(NW / 1024), blk, 0, stream>>>(Wv, Wb, NW);
    projv_gemm<<<dim3(4, 64, 1), gblk, 0, stream>>>(Xb, Wb, vT, bv,
        16384, 1024, 1024, 0, 0, 0, 1.f);

    for (int b = 0; b < 8; b++) {
      const u16* qbB = qb + (long)b * 2048 * 1024;
      const u16* kbB = kb + (long)b * 2048 * 1024;
      const u16* vTB = vT + (long)b * 1024 * 2048;
      float* outB = (float*)d_out + (long)b * 2048 * 1024;

      qk_gemm<<<dim3(8, 8, 1), gblk, 0, stream>>>(qbB, kbB, S, nullptr,
          2048, 2048, 1024, 0, 0, 0, rs);
      softmax_rows<<<dim3(2048), blk, 0, stream>>>(S, Kmask + (long)b * 2048, P);
      pv_gemm<<<dim3(4, 8, 1), gblk, 0, stream>>>(P, vTB, outB, nullptr,
          2048, 1024, 2048, 0, 0, 0, 1.f);
    }
  }
}